// Round 1
// 546.457 us; speedup vs baseline: 1.1660x; 1.1660x over previous
//
#include <hip/hip_runtime.h>
#include <stdint.h>

#define B_ROWS 8192
#define K_DIM 2048
#define N_DIM 2048
#define NPOP 8

typedef float f32x4 __attribute__((ext_vector_type(4)));
typedef __bf16 bf16x8 __attribute__((ext_vector_type(8)));

__device__ __forceinline__ unsigned short f2bf(float f) {
  unsigned int u = __float_as_uint(f);
  u += 0x7fffu + ((u >> 16) & 1u);   // round-to-nearest-even
  return (unsigned short)(u >> 16);
}

// async global->LDS, 16B per lane; LDS side = wave-uniform base + lane*16
__device__ __forceinline__ void glds16(const unsigned short* g, unsigned short* l) {
  __builtin_amdgcn_global_load_lds(
      (__attribute__((address_space(1))) unsigned int*)g,
      (__attribute__((address_space(3))) unsigned int*)l, 16, 0, 0);
}

// ---- W fp32 -> bf16 ----
__global__ void prep_w_kernel(const float* __restrict__ W, unsigned short* __restrict__ Wb) {
  const int n4 = NPOP * N_DIM * K_DIM / 4;
  int stride = gridDim.x * blockDim.x;
  for (int i = blockIdx.x * blockDim.x + threadIdx.x; i < n4; i += stride) {
    float4 v = reinterpret_cast<const float4*>(W)[i];
    ushort4 s;
    s.x = f2bf(v.x); s.y = f2bf(v.y); s.z = f2bf(v.z); s.w = f2bf(v.w);
    reinterpret_cast<ushort4*>(Wb)[i] = s;
  }
}

// ---- x fp32 -> bf16, selector logits (fp32), top-2 -> sel[row] ----
__global__ void prep_x_sel_kernel(const float* __restrict__ x,
                                  const float* __restrict__ Ws,
                                  const float* __restrict__ bs,
                                  unsigned short* __restrict__ xb,
                                  int* __restrict__ sel) {
  const int w = threadIdx.x >> 6;
  const int l = threadIdx.x & 63;
  const int r = blockIdx.x * 4 + w;   // 2048 blocks * 4 waves = 8192 rows

  float acc[NPOP];
#pragma unroll
  for (int p = 0; p < NPOP; ++p) acc[p] = 0.f;

  const float4* x4  = reinterpret_cast<const float4*>(x);
  const float4* Ws4 = reinterpret_cast<const float4*>(Ws);
#pragma unroll
  for (int j = 0; j < 8; ++j) {
    int idx = j * 256 + l * 4;
    float4 v = x4[(r * K_DIM + idx) >> 2];
    ushort4 s; s.x = f2bf(v.x); s.y = f2bf(v.y); s.z = f2bf(v.z); s.w = f2bf(v.w);
    *reinterpret_cast<ushort4*>(xb + (size_t)r * K_DIM + idx) = s;
#pragma unroll
    for (int p = 0; p < NPOP; ++p) {
      float4 wv = Ws4[(p * K_DIM + idx) >> 2];
      acc[p] += v.x * wv.x + v.y * wv.y + v.z * wv.z + v.w * wv.w;
    }
  }
#pragma unroll
  for (int off = 32; off > 0; off >>= 1)
#pragma unroll
    for (int p = 0; p < NPOP; ++p) acc[p] += __shfl_xor(acc[p], off, 64);

  if (l == 0) {
    float lg[NPOP];
#pragma unroll
    for (int p = 0; p < NPOP; ++p) lg[p] = acc[p] + bs[p];
    int p1 = 0;
#pragma unroll
    for (int p = 1; p < NPOP; ++p) if (lg[p] > lg[p1]) p1 = p;   // strict >: low index wins ties
    int p2 = -1;
#pragma unroll
    for (int p = 0; p < NPOP; ++p) {
      if (p == p1) continue;
      if (p2 < 0 || lg[p] > lg[p2]) p2 = p;
    }
    sel[r] = p1 * 8 + p2;
  }
}

// ---- build per-(slot,expert) row lists deterministically (one block per list) ----
__global__ __launch_bounds__(256) void build_lists_kernel(const int* __restrict__ sel,
                                                          int* __restrict__ lists,
                                                          int* __restrict__ cnt) {
  const int lid  = blockIdx.x;      // 0..15
  const int slot = lid >> 3;
  const int ex   = lid & 7;
  const int t    = threadIdx.x;

  __shared__ int psum[256];

  int local[32];
  int c = 0;
#pragma unroll
  for (int i = 0; i < 32; ++i) {
    int r = i * 256 + t;            // coalesced scan
    int s = sel[r];
    int e = slot ? (s & 7) : (s >> 3);
    if (e == ex) local[c++] = r;
  }
  psum[t] = c;
  __syncthreads();
  for (int off = 1; off < 256; off <<= 1) {   // Hillis-Steele inclusive scan
    int v = (t >= off) ? psum[t - off] : 0;
    __syncthreads();
    psum[t] += v;
    __syncthreads();
  }
  int start = psum[t] - c;
  for (int i = 0; i < c; ++i) lists[lid * 2048 + start + i] = local[i];
  if (t == 255) cnt[lid] = psum[255];
}

// ============================================================================
// Grouped GEMM: 256x256 tile, BK=64, 8 waves (2Mx4N), 8-phase schedule
// (T1 XCD-swizzle + T2 XOR-swizzle + T3/T4 counted vmcnt + T5 setprio).
// LDS: A[2][256][64] + B[2][256][64] bf16 = 128 KiB (2-buffer).
// Per phase: {ds_read subtile | stage 1 half-tile (2 glds/thread) | bar |
//             setprio(1) 16xMFMA setprio(0) | bar}; vmcnt(6) at phases 4,8.
// Swizzle (rule #21): LDS dest linear; global SOURCE col ^= ((l&7)^(l>>3))<<4;
// READ col ^= ((row&7)<<4). 16 lanes/row-group -> 2 lanes/bank (free).
// ============================================================================

#define BAR()  asm volatile("s_barrier" ::: "memory")
#define VMW6   asm volatile("s_waitcnt vmcnt(6)" ::: "memory")
#define VMW0   asm volatile("s_waitcnt vmcnt(0)" ::: "memory")
#define SP(x)  __builtin_amdgcn_s_setprio(x)
#define SB0()  __builtin_amdgcn_sched_barrier(0)

#define STAGE_A(buf, msel, kt) do {                                            \
    unsigned short* lb_ = &As[buf][(msel) * 8192 + w * 512];                   \
    glds16((const unsigned short*)((const char*)xb + (aoff##msel##0 + (unsigned)((kt) * 128))), lb_); \
    glds16((const unsigned short*)((const char*)xb + (aoff##msel##1 + (unsigned)((kt) * 128))), lb_ + 4096); \
  } while (0)

#define STAGE_B(buf, nsel, kt) do {                                            \
    unsigned short* lb_ = &Bs[buf][(nsel) * 8192 + w * 512];                   \
    glds16((const unsigned short*)((const char*)wgp + (boff##nsel##0 + (unsigned)((kt) * 128))), lb_); \
    glds16((const unsigned short*)((const char*)wgp + (boff##nsel##1 + (unsigned)((kt) * 128))), lb_ + 4096); \
  } while (0)

#define LOAD_AF(buf, msel) do {                                                \
    const char* ab_ = (const char*)&As[0][0] + (buf) * 32768 + (msel) * 16384 + arow_rd; \
    _Pragma("unroll") for (int mi_ = 0; mi_ < 4; ++mi_) {                      \
      af[mi_][0] = *(const bf16x8*)(ab_ + mi_ * 2048 + csw0);                  \
      af[mi_][1] = *(const bf16x8*)(ab_ + mi_ * 2048 + csw1); }                \
  } while (0)

#define LOAD_BF(dst, buf, nsel) do {                                           \
    const char* bb_ = (const char*)&Bs[0][0] + (buf) * 32768 + (nsel) * 16384 + brow_rd; \
    _Pragma("unroll") for (int ni_ = 0; ni_ < 2; ++ni_) {                      \
      dst[ni_][0] = *(const bf16x8*)(bb_ + ni_ * 2048 + csw0);                 \
      dst[ni_][1] = *(const bf16x8*)(bb_ + ni_ * 2048 + csw1); }               \
  } while (0)

#define MMA(msel, nsel, bfv) do {                                              \
    _Pragma("unroll") for (int mi_ = 0; mi_ < 4; ++mi_)                        \
    _Pragma("unroll") for (int ni_ = 0; ni_ < 2; ++ni_) {                      \
      f32x4 a_ = acc[(msel)*4+mi_][(nsel)*2+ni_];                              \
      a_ = __builtin_amdgcn_mfma_f32_16x16x32_bf16(af[mi_][0], bfv[ni_][0], a_, 0, 0, 0); \
      a_ = __builtin_amdgcn_mfma_f32_16x16x32_bf16(af[mi_][1], bfv[ni_][1], a_, 0, 0, 0); \
      acc[(msel)*4+mi_][(nsel)*2+ni_] = a_; }                                  \
  } while (0)

// One K-tile (BK=64) = 4 phases. Staging plan (derived, slot-safe):
//  p1: reads A(m0)+B(n0) [12]; stage B1 of kt+1 -> other buffer
//  p2: reads B(n1) [4];        stage A0 of kt+2 -> this buffer (A0 freed @p1)
//  p3: reads A(m1) [8];        stage B0 of kt+2 (B0 freed @p1)
//  p4: no reads;               stage A1 of kt+2 (A1 freed @p3); vmcnt at p4
#define HALF_ITER(buf, obuf, kt, DO1, DO2, VM) do {                            \
    LOAD_AF(buf, 0); LOAD_BF(bf0, buf, 0);                                     \
    if (DO1) STAGE_B(obuf, 1, (kt) + 1);                                       \
    BAR(); SP(1); MMA(0, 0, bf0); SP(0); SB0(); BAR();                         \
    LOAD_BF(bf1, buf, 1);                                                      \
    if (DO2) STAGE_A(buf, 0, (kt) + 2);                                        \
    BAR(); SP(1); MMA(0, 1, bf1); SP(0); SB0(); BAR();                         \
    LOAD_AF(buf, 1);                                                           \
    if (DO2) STAGE_B(buf, 0, (kt) + 2);                                        \
    BAR(); SP(1); MMA(1, 1, bf1); SP(0); SB0(); BAR();                         \
    if (DO2) STAGE_A(buf, 1, (kt) + 2);                                        \
    VM;                                                                        \
    BAR(); SP(1); MMA(1, 0, bf0); SP(0); SB0(); BAR();                         \
  } while (0)

#define EPILOGUE(STMT)                                                         \
  _Pragma("unroll") for (int mi8 = 0; mi8 < 8; ++mi8) {                        \
    const int rb = wm * 128 + ((mi8 >> 2) << 6) + ((mi8 & 3) << 4) + (quad << 2); \
    _Pragma("unroll") for (int j = 0; j < 4; ++j) {                            \
      int r = m0 + rb + j;                                                     \
      if (r < cg) {                                                            \
        int gr = list[r];                                                      \
        float* orow = out + (size_t)gr * N_DIM + n0 + wn * 64;                 \
        _Pragma("unroll") for (int nj = 0; nj < 4; ++nj) {                     \
          int col = ((nj >> 1) << 5) + ((nj & 1) << 4) + lane16;               \
          float v = 0.5f * acc[mi8][nj][j] + 0.5f * bv[nj];                    \
          STMT;                                                                \
        } } } }

__global__ __launch_bounds__(512, 2) void gemm_kernel(
    const unsigned short* __restrict__ xb,
    const unsigned short* __restrict__ Wb,
    const float* __restrict__ bvec,
    const int* __restrict__ lists,
    const int* __restrict__ cnt,
    float* __restrict__ out,
    int pass) {
  // flat grid 512 = 8m x 8n x 8g; low 3 bits = expert -> XCD = expert (L2 locality)
  const int bid = blockIdx.x;
  const int g   = bid & 7;
  const int mt  = (bid >> 3) & 7;
  const int nt  = bid >> 6;
  const int lid = pass * 8 + g;
  const int cg  = cnt[lid];
  const int m0  = mt * 256;
  if (m0 >= cg) return;
  const int n0 = nt * 256;

  __shared__ __align__(16) unsigned short As[2][16384];   // [buf][msel*8192 + row*64 + col]
  __shared__ __align__(16) unsigned short Bs[2][16384];

  const int t = threadIdx.x;
  const int w = t >> 6, l = t & 63;
  const int lane16 = l & 15, quad = l >> 4;
  const int wm = w >> 2, wn = w & 3;
  const int l8 = l >> 3;
  const unsigned int swS = (unsigned)(((l & 7) ^ l8) << 4);   // staging source swizzle
  const unsigned int swR = (unsigned)((l & 7) << 4);          // read swizzle (row&7 == l&7)
  const unsigned int csw0 = ((unsigned)(quad << 4)) ^ swR;            // ks=0
  const unsigned int csw1 = ((unsigned)(64 | (quad << 4))) ^ swR;     // ks=1
  const unsigned int arow_rd = (unsigned)(wm * 8192 + lane16 * 128);
  const unsigned int brow_rd = (unsigned)(wn * 4096 + lane16 * 128);

  const int* list = lists + lid * 2048;
  const unsigned short* wgp = Wb + (size_t)g * (N_DIM * K_DIM);

  // per-thread staging source offsets (row gather for A; linear W rows for B)
  const int trb = w * 8 + l8;
  int r00 = m0 + trb;        int g00 = (r00 < cg) ? list[r00] : 0;
  int r01 = m0 + 128 + trb;  int g01 = (r01 < cg) ? list[r01] : 0;
  int r10 = m0 + 64 + trb;   int g10 = (r10 < cg) ? list[r10] : 0;
  int r11 = m0 + 192 + trb;  int g11 = (r11 < cg) ? list[r11] : 0;
  const unsigned int aoff00 = (unsigned)g00 * 4096u + swS;
  const unsigned int aoff01 = (unsigned)g01 * 4096u + swS;
  const unsigned int aoff10 = (unsigned)g10 * 4096u + swS;
  const unsigned int aoff11 = (unsigned)g11 * 4096u + swS;
  const int rl0 = w * 8 + l8, rl1 = 64 + w * 8 + l8;
  const int b0 = n0 + ((rl0 >> 5) << 6) + (rl0 & 31);
  const int b1 = n0 + ((rl1 >> 5) << 6) + (rl1 & 31);
  const unsigned int boff00 = (unsigned)b0 * 4096u + swS;
  const unsigned int boff01 = (unsigned)b1 * 4096u + swS;
  const unsigned int boff10 = boff00 + 32u * 4096u;
  const unsigned int boff11 = boff01 + 32u * 4096u;

  bf16x8 af[4][2], bf0[2][2], bf1[2][2];
  f32x4 acc[8][4];
#pragma unroll
  for (int i = 0; i < 8; ++i)
#pragma unroll
    for (int jq = 0; jq < 4; ++jq) { f32x4 z = {0.f, 0.f, 0.f, 0.f}; acc[i][jq] = z; }

  // prologue: kt0 fully + kt1 {A0,B0,A1}; leave 3 half-tiles (6 loads) in flight
  STAGE_A(0, 0, 0); STAGE_B(0, 0, 0); STAGE_A(0, 1, 0); STAGE_B(0, 1, 0);
  STAGE_A(1, 0, 1); STAGE_B(1, 0, 1); STAGE_A(1, 1, 1);
  VMW6;
  BAR();

  // 32 K-tiles of 64; steady state stages kt+1(B1)/kt+2(A0,B0,A1)
#pragma unroll 1
  for (int h = 0; h < 30; h += 2) {
    HALF_ITER(0, 1, h,     1, 1, VMW6);
    HALF_ITER(1, 0, h + 1, 1, 1, VMW6);
  }
  HALF_ITER(0, 1, 30, 1, 0, VMW0);
  HALF_ITER(1, 0, 31, 0, 0, (void)0);

  // epilogue: direct global reads for list/bias (no LDS)
  const float* bias = bvec + (size_t)g * N_DIM + n0 + wn * 64;
  float bv[4];
#pragma unroll
  for (int nj = 0; nj < 4; ++nj) bv[nj] = bias[((nj >> 1) << 5) + ((nj & 1) << 4) + lane16];

  if (pass == 0) { EPILOGUE(orow[col] = v); }
  else           { EPILOGUE(orow[col] += v); }
}

extern "C" void kernel_launch(void* const* d_in, const int* in_sizes, int n_in,
                              void* d_out, int out_size, void* d_ws, size_t ws_size,
                              hipStream_t stream) {
  const float* x  = (const float*)d_in[0];
  const float* W  = (const float*)d_in[1];
  const float* b  = (const float*)d_in[2];
  const float* Ws = (const float*)d_in[3];
  const float* bs = (const float*)d_in[4];
  float* out = (float*)d_out;

  // ws: Wb bf16 (64MiB) | xb bf16 (32MiB) | lists 16*2048 int | cnt 16 int | sel 8192 int
  char* ws = (char*)d_ws;
  unsigned short* Wb = (unsigned short*)ws;
  unsigned short* xb = (unsigned short*)(ws + (size_t)67108864);
  int* lists = (int*)(ws + (size_t)67108864 + 33554432);
  int* cnt   = (int*)(ws + (size_t)67108864 + 33554432 + 131072);
  int* sel   = (int*)(ws + (size_t)67108864 + 33554432 + 131072 + 4096);

  prep_w_kernel<<<4096, 256, 0, stream>>>(W, Wb);
  prep_x_sel_kernel<<<2048, 256, 0, stream>>>(x, Ws, bs, xb, sel);
  build_lists_kernel<<<16, 256, 0, stream>>>(sel, lists, cnt);
  gemm_kernel<<<dim3(512), dim3(512), 0, stream>>>(xb, Wb, b, lists, cnt, out, 0);
  gemm_kernel<<<dim3(512), dim3(512), 0, stream>>>(xb, Wb, b, lists, cnt, out, 1);
}